// Round 9
// baseline (823.109 us; speedup 1.0000x reference)
//
#include <hip/hip_runtime.h>
#include <cstdint>
#include <cstddef>

#define T_TOTAL   131072
#define NWORDS    32768
#define WDIM      1024
#define CDIM      256
#define HID       512
#define NEMB      40
#define KDIM      1024
#define NDIM      1024

// ---- 256^2 GEMM geometry (BK=32, 2-phase K-steps, 4-buffer ring) ----
#define GBM 256
#define GBN 256
#define NKV 96          // virtual K steps: 3 products x 32 steps of K=1024
// ---- legacy 128^2 fallback geometry ----
#define BM 128
#define BN 128
#define BK 32
#define NK (KDIM / BK)
#define EPS 132

#define NCONVB_BLKS (NDIM * KDIM / 4 / 256)          // 1024
#define NCONVA_BLKS (NWORDS * KDIM / 4 / 256)        // 32768

typedef __attribute__((ext_vector_type(8))) short bf16x8;
typedef __attribute__((ext_vector_type(4))) float f32x4;
typedef __attribute__((ext_vector_type(4))) unsigned short u16x4;

__device__ __forceinline__ unsigned short f2bf(float x) {
  union { float f; unsigned int u; } v; v.f = x;
  unsigned int r = v.u + 0x7fffu + ((v.u >> 16) & 1u);   // RNE
  return (unsigned short)(r >> 16);
}
__device__ __forceinline__ float bf2f(unsigned short b) {
  union { float f; unsigned int u; } v; v.u = ((unsigned int)b) << 16;
  return v.f;
}

__device__ __forceinline__ void gld16(const void* src, void* lds) {
  __builtin_amdgcn_global_load_lds(
      (const __attribute__((address_space(1))) unsigned int*)src,
      (__attribute__((address_space(3))) unsigned int*)lds, 16, 0, 0);
}

// ---------------- fused prep: LSTM->Hc, W_lin->Bh/Bl, word_emb->Ah/Al ----------------
template <bool DO_A>
__global__ __launch_bounds__(256) void k_prep(
    const float* __restrict__ word_emb, const float* __restrict__ E,
    const float* __restrict__ W_ih, const float* __restrict__ b_ih,
    const float* __restrict__ b_hh, const float* __restrict__ W_lin,
    const float* __restrict__ b_lin,
    unsigned short* __restrict__ Ah, unsigned short* __restrict__ Al,
    unsigned short* __restrict__ Bh, unsigned short* __restrict__ Bl,
    float* __restrict__ Hc) {
  __shared__ float sx[CDIM];
  __shared__ float sh[HID];
  int b = blockIdx.x;
  int tid = threadIdx.x;

  if (b < NEMB) {
    int e = b;
    sx[tid] = E[e * CDIM + tid];
    __syncthreads();
    const float4* xv = (const float4*)sx;
#pragma unroll
    for (int rep = 0; rep < 2; ++rep) {
      int j = rep * 256 + tid;
      float si = b_ih[j] + b_hh[j];
      float sg = b_ih[1024 + j] + b_hh[1024 + j];
      float so = b_ih[1536 + j] + b_hh[1536 + j];
      const float4* wi = (const float4*)&W_ih[(size_t)j * CDIM];
      const float4* wg = (const float4*)&W_ih[(size_t)(1024 + j) * CDIM];
      const float4* wo = (const float4*)&W_ih[(size_t)(1536 + j) * CDIM];
      for (int k = 0; k < CDIM / 4; ++k) {
        float4 d = xv[k];
        float4 a = wi[k]; si += a.x*d.x + a.y*d.y + a.z*d.z + a.w*d.w;
        float4 g = wg[k]; sg += g.x*d.x + g.y*d.y + g.z*d.z + g.w*d.w;
        float4 c = wo[k]; so += c.x*d.x + c.y*d.y + c.z*d.z + c.w*d.w;
      }
      float iv = 1.f / (1.f + expf(-si));
      float cv = iv * tanhf(sg);
      float ov = 1.f / (1.f + expf(-so));
      sh[j] = ov * tanhf(cv);
    }
    __syncthreads();
    const float4* hv = (const float4*)sh;
#pragma unroll
    for (int rep = 0; rep < 4; ++rep) {
      int n = rep * 256 + tid;
      float s = b_lin[n];
      const float4* wl = (const float4*)&W_lin[(size_t)n * 1536 + 1024];
      for (int k = 0; k < HID / 4; ++k) {
        float4 a = wl[k], d = hv[k];
        s += a.x*d.x + a.y*d.y + a.z*d.z + a.w*d.w;
      }
      Hc[e * NDIM + n] = s;
    }
    return;
  }
  b -= NEMB;
  if (b < NCONVB_BLKS) {
    long idx = ((long)b * 256 + tid) * 4;
    long r = idx >> 10;
    int c = (int)(idx & 1023);
    const float4 v = *(const float4*)&W_lin[r * 1536 + c];
    unsigned short h0 = f2bf(v.x), h1 = f2bf(v.y), h2 = f2bf(v.z), h3 = f2bf(v.w);
    u16x4 H = {h0, h1, h2, h3};
    u16x4 L = {f2bf(v.x - bf2f(h0)), f2bf(v.y - bf2f(h1)),
               f2bf(v.z - bf2f(h2)), f2bf(v.w - bf2f(h3))};
    *(u16x4*)&Bh[idx] = H;
    *(u16x4*)&Bl[idx] = L;
    return;
  }
  if (DO_A) {
    b -= NCONVB_BLKS;
    long idx = ((long)b * 256 + tid) * 4;
    const float4 v = *(const float4*)&word_emb[idx];
    unsigned short h0 = f2bf(v.x), h1 = f2bf(v.y), h2 = f2bf(v.z), h3 = f2bf(v.w);
    u16x4 H = {h0, h1, h2, h3};
    u16x4 L = {f2bf(v.x - bf2f(h0)), f2bf(v.y - bf2f(h1)),
               f2bf(v.z - bf2f(h2)), f2bf(v.w - bf2f(h3))};
    *(u16x4*)&Ah[idx] = H;
    *(u16x4*)&Al[idx] = L;
  }
}

// ---------------- 256^2 GEMM -> P[32768][1024], 2-phase K-steps ----------------
// P = Ah*Bh^T + Ah*Bl^T + Al*Bh^T as one virtual-K=3072 bf16 GEMM.
// 512 thr / 8 waves (2M x 4N, wave tile 128x64). BK=32 -> 96 virtual K-steps.
// 4-buffer LDS ring (4 x 32KB = 128KB), prefetch distance 2 K-steps.
// Each K-step = 2 phases; each phase:
//   {ds_read subtile || stage 1 half-tile (2 gld16)} -> s_barrier ->
//   lgkmcnt(0) -> sched_barrier -> setprio(1) 16 MFMA setprio(0) -> s_barrier
// vmcnt(4) ONCE per K-step (phase B), never 0 until tail (T4 counted-vmcnt).
// XOR slot-swizzle on global source + frag reads (64B rows) -> 0 conflicts.
__global__ __launch_bounds__(512, 2) void k_gemm_p256(
    const unsigned short* __restrict__ Ah, const unsigned short* __restrict__ Al,
    const unsigned short* __restrict__ Bh, const unsigned short* __restrict__ Bl,
    float* __restrict__ P) {
  __shared__ __align__(16) char smem[131072];   // 4 x [A 16KB | B 16KB]

  int bid = blockIdx.x;                         // 512 blocks
  int swz = (bid & 7) * 64 + (bid >> 3);        // XCD-contiguous
  int bm = swz >> 2;                            // 0..127
  int bn = swz & 3;                             // 0..3

  int tid = threadIdx.x;
  int lane = tid & 63;
  int w = tid >> 6;                             // 0..7
  int wm = w >> 2, wn = w & 3;                  // 2 x 4 wave grid
  int fr = lane & 15, fq = lane >> 4;

  size_t arow0 = (size_t)bm * GBM;
  size_t brow0 = (size_t)bn * GBN;

  f32x4 acc[8][4];
#pragma unroll
  for (int i = 0; i < 8; ++i)
#pragma unroll
    for (int j = 0; j < 4; ++j) acc[i][j] = (f32x4)0.0f;

  // staging descriptors: 2 x 16B per thread per matrix; half l covers rows [l*128, +128)
  size_t aS[2], bS[2];
  int sL[2];
#pragma unroll
  for (int l = 0; l < 2; ++l) {
    int off = l * 8192 + tid * 16;              // byte off in 16KB region
    int r = off >> 6;                           // row 0..255 (64B rows)
    int sp = (off >> 4) & 3;                    // 16B slot
    int colE = ((sp ^ ((r >> 1) & 3)) << 3);    // swizzled source col (bf16)
    aS[l] = (arow0 + r) * KDIM + colE;
    bS[l] = (brow0 + r) * KDIM + colE;
    sL[l] = l * 8192 + w * 1024;                // wave-uniform LDS base
  }
  // fragment read offsets (swizzled)
  int aOff[8], bOff[4];
#pragma unroll
  for (int mi = 0; mi < 8; ++mi) {
    int row = wm * 128 + mi * 16 + fr;
    aOff[mi] = row * 64 + ((fq ^ ((row >> 1) & 3)) << 4);
  }
#pragma unroll
  for (int ni = 0; ni < 4; ++ni) {
    int row = wn * 64 + ni * 16 + fr;
    bOff[ni] = row * 64 + ((fq ^ ((row >> 1) & 3)) << 4);
  }

  auto STAGE_H = [&](int buf, int vt, int l) {  // 2 gld16 / thread
    const unsigned short* aB = (vt < 64) ? Ah : Al;
    const unsigned short* bB = (vt < 32) ? Bh : ((vt < 64) ? Bl : Bh);
    int k0 = (vt & 31) << 5;
    char* L = smem + buf * 32768;
    gld16(aB + aS[l] + k0, L + sL[l]);
    gld16(bB + bS[l] + k0, L + 16384 + sL[l]);
  };

  // prologue: steps 0,1 fully staged
  STAGE_H(0, 0, 0); STAGE_H(0, 0, 1);
  STAGE_H(1, 1, 0); STAGE_H(1, 1, 1);
  asm volatile("s_waitcnt vmcnt(4)" ::: "memory");   // step 0 landed, step 1 flying
  __builtin_amdgcn_s_barrier();
  __builtin_amdgcn_sched_barrier(0);

  for (int t = 0; t < NKV; ++t) {
    char* bufc = smem + (t & 3) * 32768;

    // ---- phase A: read B frags + A frags mi0-3, stage half 0 of step t+2
    bf16x8 fb[4], fa[4];
#pragma unroll
    for (int ni = 0; ni < 4; ++ni)
      fb[ni] = *(const bf16x8*)(bufc + 16384 + bOff[ni]);
#pragma unroll
    for (int mi = 0; mi < 4; ++mi)
      fa[mi] = *(const bf16x8*)(bufc + aOff[mi]);
    if (t + 2 < NKV) STAGE_H((t + 2) & 3, t + 2, 0);
    __builtin_amdgcn_s_barrier();
    asm volatile("s_waitcnt lgkmcnt(0)" ::: "memory");
    __builtin_amdgcn_sched_barrier(0);
    __builtin_amdgcn_s_setprio(1);
#pragma unroll
    for (int mi = 0; mi < 4; ++mi)
#pragma unroll
      for (int ni = 0; ni < 4; ++ni)
        acc[mi][ni] = __builtin_amdgcn_mfma_f32_16x16x32_bf16(fa[mi], fb[ni], acc[mi][ni], 0, 0, 0);
    __builtin_amdgcn_s_setprio(0);
    __builtin_amdgcn_sched_barrier(0);
    __builtin_amdgcn_s_barrier();

    // ---- phase B: read A frags mi4-7, stage half 1 of step t+2, counted vmcnt
    bf16x8 fa2[4];
#pragma unroll
    for (int mi = 0; mi < 4; ++mi)
      fa2[mi] = *(const bf16x8*)(bufc + aOff[4 + mi]);
    if (t + 2 < NKV) STAGE_H((t + 2) & 3, t + 2, 1);
    if (t < NKV - 2) {
      asm volatile("s_waitcnt vmcnt(4)" ::: "memory");  // step t+1 landed, t+2 flying
    } else {
      asm volatile("s_waitcnt vmcnt(0)" ::: "memory");
    }
    __builtin_amdgcn_s_barrier();
    asm volatile("s_waitcnt lgkmcnt(0)" ::: "memory");
    __builtin_amdgcn_sched_barrier(0);
    __builtin_amdgcn_s_setprio(1);
#pragma unroll
    for (int mi = 0; mi < 4; ++mi)
#pragma unroll
      for (int ni = 0; ni < 4; ++ni)
        acc[4 + mi][ni] = __builtin_amdgcn_mfma_f32_16x16x32_bf16(fa2[mi], fb[ni], acc[4 + mi][ni], 0, 0, 0);
    __builtin_amdgcn_s_setprio(0);
    __builtin_amdgcn_sched_barrier(0);
    __builtin_amdgcn_s_barrier();
  }

  // ---- epilogue: direct stores (quarter-wave 64B coalesced, L2/L3-resident)
  // frag layout: row = wm*128 + mi*16 + fq*4 + j, col = wn*64 + ni*16 + fr
  size_t pbase = (arow0 + wm * 128) * NDIM + brow0 + wn * 64 + fr;
#pragma unroll
  for (int mi = 0; mi < 8; ++mi)
#pragma unroll
    for (int j = 0; j < 4; ++j) {
      size_t rowoff = (size_t)(mi * 16 + fq * 4 + j) * NDIM;
#pragma unroll
      for (int ni = 0; ni < 4; ++ni)
        P[pbase + rowoff + ni * 16] = acc[mi][ni][j];
    }
}

// ---------------- legacy 128^2 fallback (fp32 A staged, split in-kernel) ----------------
__global__ __launch_bounds__(256, 2) void k_gemm_p_f32(
    const float* __restrict__ Af,
    const unsigned short* __restrict__ Bh, const unsigned short* __restrict__ Bl,
    float* __restrict__ P) {
  __shared__ __align__(16) char smem[65536];

  int nwg = gridDim.x;
  int bid = blockIdx.x;
  int cpx = nwg >> 3;
  int swz = (bid & 7) * cpx + (bid >> 3);
  int bn = swz & 7;
  int bm = swz >> 3;

  int tid = threadIdx.x;
  int lane = tid & 63;
  int w = tid >> 6;
  int wr = w >> 1, wc = w & 1;
  int fr = lane & 15, fq = lane >> 4;

  size_t arow0 = (size_t)bm * BM;
  size_t brow0 = (size_t)bn * BN;

  f32x4 acc[4][4];
#pragma unroll
  for (int i = 0; i < 4; ++i)
#pragma unroll
    for (int j = 0; j < 4; ++j) acc[i][j] = (f32x4)0.0f;

  int bOff[4];
#pragma unroll
  for (int ni = 0; ni < 4; ++ni) {
    int row = wc * 64 + ni * 16 + fr;
    bOff[ni] = row * 64 + ((fq ^ ((row >> 1) & 3)) << 4);
  }
  size_t bS[2]; int bL[2];
#pragma unroll
  for (int is = 0; is < 2; ++is) {
    int off = is * 4096 + tid * 16;
    int r = off >> 6;
    int sp = (off >> 4) & 3;
    int colE = ((sp ^ ((r >> 1) & 3)) << 3);
    bS[is] = (brow0 + r) * KDIM + colE;
    bL[is] = is * 4096 + w * 1024;
  }
  size_t aS[4]; int aL[4];
#pragma unroll
  for (int is = 0; is < 4; ++is) {
    int off = is * 4096 + tid * 16;
    int r = off >> 7;
    int sl = (off >> 4) & 7;
    int col = ((sl ^ (r & 7)) << 2);
    aS[is] = (arow0 + r) * KDIM + col;
    aL[is] = is * 4096 + w * 1024;
  }
  int a1[4], a2[4];
#pragma unroll
  for (int mi = 0; mi < 4; ++mi) {
    int row = wr * 64 + mi * 16 + fr;
    a1[mi] = row * 128 + (((fq << 1)     ^ (row & 7)) << 4);
    a2[mi] = row * 128 + (((fq << 1) + 1) ^ (row & 7)) * 16;
  }

  auto STAGE = [&](int buf, int k0) {
    char* b = smem + buf * 32768;
#pragma unroll
    for (int is = 0; is < 4; ++is) gld16(Af + aS[is] + k0, b + aL[is]);
#pragma unroll
    for (int is = 0; is < 2; ++is) {
      gld16(Bh + bS[is] + k0, b + 16384 + bL[is]);
      gld16(Bl + bS[is] + k0, b + 24576 + bL[is]);
    }
  };

  STAGE(0, 0);
  for (int t = 0; t < NK; ++t) {
    char* bufc = smem + (t & 1) * 32768;
    if (t + 1 < NK) {
      STAGE((t + 1) & 1, (t + 1) * BK);
      asm volatile("s_waitcnt vmcnt(8)" ::: "memory");
    } else {
      asm volatile("s_waitcnt vmcnt(0)" ::: "memory");
    }
    __builtin_amdgcn_s_barrier();
    __builtin_amdgcn_sched_barrier(0);

    bf16x8 fah[4], fal[4], fbh[4], fbl[4];
#pragma unroll
    for (int ni = 0; ni < 4; ++ni) {
      fbh[ni] = *(const bf16x8*)(bufc + 16384 + bOff[ni]);
      fbl[ni] = *(const bf16x8*)(bufc + 24576 + bOff[ni]);
    }
#pragma unroll
    for (int mi = 0; mi < 4; ++mi) {
      float4 v1 = *(const float4*)(bufc + a1[mi]);
      float4 v2 = *(const float4*)(bufc + a2[mi]);
      float f[8] = {v1.x, v1.y, v1.z, v1.w, v2.x, v2.y, v2.z, v2.w};
      union { bf16x8 v; unsigned short u[8]; } H, L;
#pragma unroll
      for (int q = 0; q < 8; ++q) {
        unsigned short hq = f2bf(f[q]);
        H.u[q] = hq;
        L.u[q] = f2bf(f[q] - bf2f(hq));
      }
      fah[mi] = H.v;
      fal[mi] = L.v;
    }
    __builtin_amdgcn_s_setprio(1);
#pragma unroll
    for (int mi = 0; mi < 4; ++mi)
#pragma unroll
      for (int ni = 0; ni < 4; ++ni) {
        acc[mi][ni] = __builtin_amdgcn_mfma_f32_16x16x32_bf16(fah[mi], fbh[ni], acc[mi][ni], 0, 0, 0);
        acc[mi][ni] = __builtin_amdgcn_mfma_f32_16x16x32_bf16(fah[mi], fbl[ni], acc[mi][ni], 0, 0, 0);
        acc[mi][ni] = __builtin_amdgcn_mfma_f32_16x16x32_bf16(fal[mi], fbh[ni], acc[mi][ni], 0, 0, 0);
      }
    __builtin_amdgcn_s_setprio(0);
    __builtin_amdgcn_sched_barrier(0);
    __builtin_amdgcn_s_barrier();
  }

  float* ep = (float*)smem;
  __syncthreads();
#pragma unroll
  for (int half = 0; half < 2; ++half) {
    if (wr == half) {
#pragma unroll
      for (int mi = 0; mi < 4; ++mi)
#pragma unroll
        for (int ni = 0; ni < 4; ++ni)
#pragma unroll
          for (int j = 0; j < 4; ++j) {
            int r = mi * 16 + fq * 4 + j;
            int c = wc * 64 + ni * 16 + fr;
            ep[r * EPS + c] = acc[mi][ni][j];
          }
    }
    __syncthreads();
    for (int i = tid; i < 2048; i += 256) {
      int r = i >> 5;
      int c4 = (i & 31) << 2;
      float4 v = *(const float4*)&ep[r * EPS + c4];
      *(float4*)&P[(arow0 + half * 64 + r) * NDIM + brow0 + c4] = v;
    }
    __syncthreads();
  }
}

// ---------------- pass 2: streaming gather/write (warp-per-row) ----------------
__global__ __launch_bounds__(256) void k_out(const int* __restrict__ wid,
                                             const int* __restrict__ cid,
                                             const float* __restrict__ P,
                                             const float* __restrict__ Hc,
                                             float* __restrict__ out) {
  int w = threadIdx.x >> 6, lane = threadIdx.x & 63;
  int t = blockIdx.x * 4 + w;
  int wd = wid[t], cd = cid[t];
  const f32x4* pr = (const f32x4*)&P[(size_t)wd << 10];
  const f32x4* hr = (const f32x4*)&Hc[(size_t)cd << 10];
  f32x4* orow = (f32x4*)&out[(size_t)t << 10];
#pragma unroll
  for (int ch = 0; ch < 4; ++ch) {
    int c = ch * 64 + lane;
    f32x4 a = pr[c];
    f32x4 h4 = hr[c];
    f32x4 r;
    r[0] = fmaxf(a[0] + h4[0], 0.f);
    r[1] = fmaxf(a[1] + h4[1], 0.f);
    r[2] = fmaxf(a[2] + h4[2], 0.f);
    r[3] = fmaxf(a[3] + h4[3], 0.f);
    __builtin_nontemporal_store(r, &orow[c]);
  }
}

extern "C" void kernel_launch(void* const* d_in, const int* in_sizes, int n_in,
                              void* d_out, int out_size, void* d_ws, size_t ws_size,
                              hipStream_t stream) {
  (void)in_sizes; (void)n_in; (void)out_size;
  const float* word_emb = (const float*)d_in[0];
  const int*   char_ids = (const int*)d_in[1];
  const int*   word_ids = (const int*)d_in[2];
  const float* E        = (const float*)d_in[3];
  const float* W_ih     = (const float*)d_in[4];
  const float* b_ih     = (const float*)d_in[5];
  const float* b_hh     = (const float*)d_in[6];
  const float* W_lin    = (const float*)d_in[7];
  const float* b_lin    = (const float*)d_in[8];
  float* out = (float*)d_out;
  char* ws = (char*)d_ws;

  size_t o = 0;
  auto alloc = [&](size_t b) { size_t r = o; o = (o + b + 255) & ~(size_t)255; return r; };
  size_t oHc = alloc((size_t)NEMB * NDIM * 4);
  size_t oBh = alloc((size_t)NDIM * KDIM * 2);
  size_t oBl = alloc((size_t)NDIM * KDIM * 2);
  size_t oP  = alloc((size_t)NWORDS * NDIM * 4);
  size_t szB = o;
  size_t oAh = alloc((size_t)NWORDS * KDIM * 2);
  size_t oAl = alloc((size_t)NWORDS * KDIM * 2);
  size_t szA = o;

  float* Hc          = (float*)(ws + oHc);
  unsigned short* Bh = (unsigned short*)(ws + oBh);
  unsigned short* Bl = (unsigned short*)(ws + oBl);
  float* P           = (float*)(ws + oP);
  unsigned short* Ah = (unsigned short*)(ws + oAh);
  unsigned short* Al = (unsigned short*)(ws + oAl);

  if (ws_size >= szA) {
    k_prep<true><<<NEMB + NCONVB_BLKS + NCONVA_BLKS, 256, 0, stream>>>(
        word_emb, E, W_ih, b_ih, b_hh, W_lin, b_lin, Ah, Al, Bh, Bl, Hc);
    k_gemm_p256<<<(NWORDS / GBM) * (NDIM / GBN), 512, 0, stream>>>(Ah, Al, Bh, Bl, P);
  } else {
    k_prep<false><<<NEMB + NCONVB_BLKS, 256, 0, stream>>>(
        word_emb, E, W_ih, b_ih, b_hh, W_lin, b_lin, nullptr, nullptr, Bh, Bl, Hc);
    k_gemm_p_f32<<<(NWORDS / BM) * (NDIM / BN), 256, 0, stream>>>(word_emb, Bh, Bl, P);
  }
  k_out<<<T_TOTAL / 4, 256, 0, stream>>>(word_ids, char_ids, P, Hc, out);
}

// Round 11
// 480.485 us; speedup vs baseline: 1.7131x; 1.7131x over previous
//
#include <hip/hip_runtime.h>
#include <cstdint>
#include <cstddef>

#define T_TOTAL   131072
#define NWORDS    32768
#define WDIM      1024
#define CDIM      256
#define HID       512
#define NEMB      40
#define KDIM      1024
#define NDIM      1024

#define BM 128
#define BN 128
#define BK 32
#define NK (KDIM / BK)
#define EPS 132   // epilogue LDS row stride (floats): 528B -> bank-even

#define NCONVB_BLKS (NDIM * KDIM / 4 / 256)          // 1024
#define NCONVA_BLKS (NWORDS * KDIM / 4 / 256)        // 32768

typedef __attribute__((ext_vector_type(8))) short bf16x8;
typedef __attribute__((ext_vector_type(4))) float f32x4;
typedef __attribute__((ext_vector_type(4))) unsigned short u16x4;

__device__ __forceinline__ unsigned short f2bf(float x) {
  union { float f; unsigned int u; } v; v.f = x;
  unsigned int r = v.u + 0x7fffu + ((v.u >> 16) & 1u);   // RNE
  return (unsigned short)(r >> 16);
}
__device__ __forceinline__ float bf2f(unsigned short b) {
  union { float f; unsigned int u; } v; v.u = ((unsigned int)b) << 16;
  return v.f;
}

__device__ __forceinline__ void gld16(const void* src, void* lds) {
  __builtin_amdgcn_global_load_lds(
      (const __attribute__((address_space(1))) unsigned int*)src,
      (__attribute__((address_space(3))) unsigned int*)lds, 16, 0, 0);
}

// ---------------- fused prep: LSTM->Hc, W_lin->Bh/Bl, word_emb->Ah/Al ----------------
template <bool DO_A>
__global__ __launch_bounds__(256) void k_prep(
    const float* __restrict__ word_emb, const float* __restrict__ E,
    const float* __restrict__ W_ih, const float* __restrict__ b_ih,
    const float* __restrict__ b_hh, const float* __restrict__ W_lin,
    const float* __restrict__ b_lin,
    unsigned short* __restrict__ Ah, unsigned short* __restrict__ Al,
    unsigned short* __restrict__ Bh, unsigned short* __restrict__ Bl,
    float* __restrict__ Hc) {
  __shared__ float sx[CDIM];
  __shared__ float sh[HID];
  int b = blockIdx.x;
  int tid = threadIdx.x;

  if (b < NEMB) {
    // ---- fused LSTM cell (zero state) + Hc row: Hc[e] = W2 @ h + b_lin
    int e = b;
    sx[tid] = E[e * CDIM + tid];
    __syncthreads();
    const float4* xv = (const float4*)sx;
#pragma unroll
    for (int rep = 0; rep < 2; ++rep) {
      int j = rep * 256 + tid;                       // j in [0,512)
      float si = b_ih[j] + b_hh[j];
      float sg = b_ih[1024 + j] + b_hh[1024 + j];
      float so = b_ih[1536 + j] + b_hh[1536 + j];
      const float4* wi = (const float4*)&W_ih[(size_t)j * CDIM];
      const float4* wg = (const float4*)&W_ih[(size_t)(1024 + j) * CDIM];
      const float4* wo = (const float4*)&W_ih[(size_t)(1536 + j) * CDIM];
      for (int k = 0; k < CDIM / 4; ++k) {
        float4 d = xv[k];
        float4 a = wi[k]; si += a.x*d.x + a.y*d.y + a.z*d.z + a.w*d.w;
        float4 g = wg[k]; sg += g.x*d.x + g.y*d.y + g.z*d.z + g.w*d.w;
        float4 c = wo[k]; so += c.x*d.x + c.y*d.y + c.z*d.z + c.w*d.w;
      }
      float iv = 1.f / (1.f + expf(-si));
      float cv = iv * tanhf(sg);
      float ov = 1.f / (1.f + expf(-so));
      sh[j] = ov * tanhf(cv);
    }
    __syncthreads();
    const float4* hv = (const float4*)sh;
#pragma unroll
    for (int rep = 0; rep < 4; ++rep) {
      int n = rep * 256 + tid;
      float s = b_lin[n];
      const float4* wl = (const float4*)&W_lin[(size_t)n * 1536 + 1024];
      for (int k = 0; k < HID / 4; ++k) {
        float4 a = wl[k], d = hv[k];
        s += a.x*d.x + a.y*d.y + a.z*d.z + a.w*d.w;
      }
      Hc[e * NDIM + n] = s;
    }
    return;
  }
  b -= NEMB;
  if (b < NCONVB_BLKS) {
    // ---- W_lin cols [0,1024) -> Bh/Bl (hi/lo bf16 split)
    long idx = ((long)b * 256 + tid) * 4;
    long r = idx >> 10;
    int c = (int)(idx & 1023);
    const float4 v = *(const float4*)&W_lin[r * 1536 + c];
    unsigned short h0 = f2bf(v.x), h1 = f2bf(v.y), h2 = f2bf(v.z), h3 = f2bf(v.w);
    u16x4 H = {h0, h1, h2, h3};
    u16x4 L = {f2bf(v.x - bf2f(h0)), f2bf(v.y - bf2f(h1)),
               f2bf(v.z - bf2f(h2)), f2bf(v.w - bf2f(h3))};
    *(u16x4*)&Bh[idx] = H;
    *(u16x4*)&Bl[idx] = L;
    return;
  }
  if (DO_A) {
    // ---- word_emb (contiguous 32768x1024) -> Ah/Al
    b -= NCONVB_BLKS;
    long idx = ((long)b * 256 + tid) * 4;
    const float4 v = *(const float4*)&word_emb[idx];
    unsigned short h0 = f2bf(v.x), h1 = f2bf(v.y), h2 = f2bf(v.z), h3 = f2bf(v.w);
    u16x4 H = {h0, h1, h2, h3};
    u16x4 L = {f2bf(v.x - bf2f(h0)), f2bf(v.y - bf2f(h1)),
               f2bf(v.z - bf2f(h2)), f2bf(v.w - bf2f(h3))};
    *(u16x4*)&Ah[idx] = H;
    *(u16x4*)&Al[idx] = L;
  }
}

// ---------------- GEMM (dedup'd words) -> P[32768][1024] ----------------
// P[m][n] = sum_k we[m][k] * W_lin[n][k] via split-bf16 3-MFMA emulation.
// 256 thr / 4 waves (2x2, wave tile 64x64), 2 x 32KB dbuf, counted vmcnt.
// XOR slot-swizzle on the GLOBAL source (LDS dest linear, required by
// global_load_lds) and on the fragment reads -> 0 bank conflicts.
template <bool PRECONV>
__global__ __launch_bounds__(256, 2) void k_gemm_p(
    const float* __restrict__ Af,
    const unsigned short* __restrict__ Ah, const unsigned short* __restrict__ Al,
    const unsigned short* __restrict__ Bh, const unsigned short* __restrict__ Bl,
    float* __restrict__ P) {
  __shared__ __align__(16) char smem[65536];

  int nwg = gridDim.x;
  int bid = blockIdx.x;
  int cpx = nwg >> 3;
  int swz = (bid & 7) * cpx + (bid >> 3);
  int bn = swz & 7;
  int bm = swz >> 3;

  int tid = threadIdx.x;
  int lane = tid & 63;
  int w = tid >> 6;
  int wr = w >> 1, wc = w & 1;
  int fr = lane & 15, fq = lane >> 4;

  size_t arow0 = (size_t)bm * BM;
  size_t brow0 = (size_t)bn * BN;

  f32x4 acc[4][4];
#pragma unroll
  for (int i = 0; i < 4; ++i)
#pragma unroll
    for (int j = 0; j < 4; ++j) acc[i][j] = (f32x4)0.0f;

  int bOff[4];
#pragma unroll
  for (int ni = 0; ni < 4; ++ni) {
    int row = wc * 64 + ni * 16 + fr;
    bOff[ni] = row * 64 + ((fq ^ ((row >> 1) & 3)) << 4);
  }
  size_t bS[2]; int bL[2];
#pragma unroll
  for (int is = 0; is < 2; ++is) {
    int off = is * 4096 + tid * 16;
    int r = off >> 6;
    int sp = (off >> 4) & 3;
    int colE = ((sp ^ ((r >> 1) & 3)) << 3);
    bS[is] = (brow0 + r) * KDIM + colE;
    bL[is] = is * 4096 + w * 1024;
  }

  if (PRECONV) {
    size_t aS[2];
#pragma unroll
    for (int is = 0; is < 2; ++is) {
      int off = is * 4096 + tid * 16;
      int r = off >> 6;
      int sp = (off >> 4) & 3;
      int colE = ((sp ^ ((r >> 1) & 3)) << 3);
      aS[is] = (arow0 + r) * KDIM + colE;
    }
    int aOff[4];
#pragma unroll
    for (int mi = 0; mi < 4; ++mi) {
      int row = wr * 64 + mi * 16 + fr;
      aOff[mi] = row * 64 + ((fq ^ ((row >> 1) & 3)) << 4);
    }

    auto STAGE = [&](int buf, int k0) {     // 8 gld16 / thread
      char* b = smem + buf * 32768;
#pragma unroll
      for (int is = 0; is < 2; ++is) {
        gld16(Ah + aS[is] + k0, b + bL[is]);
        gld16(Al + aS[is] + k0, b + 8192 + bL[is]);
        gld16(Bh + bS[is] + k0, b + 16384 + bL[is]);
        gld16(Bl + bS[is] + k0, b + 24576 + bL[is]);
      }
    };

    STAGE(0, 0);
    for (int t = 0; t < NK; ++t) {
      char* bufc = smem + (t & 1) * 32768;
      if (t + 1 < NK) {
        STAGE((t + 1) & 1, (t + 1) * BK);
        asm volatile("s_waitcnt vmcnt(8)" ::: "memory");
      } else {
        asm volatile("s_waitcnt vmcnt(0)" ::: "memory");
      }
      __builtin_amdgcn_s_barrier();
      __builtin_amdgcn_sched_barrier(0);

      bf16x8 fah[4], fal[4], fbh[4], fbl[4];
#pragma unroll
      for (int ni = 0; ni < 4; ++ni) {
        fbh[ni] = *(const bf16x8*)(bufc + 16384 + bOff[ni]);
        fbl[ni] = *(const bf16x8*)(bufc + 24576 + bOff[ni]);
      }
#pragma unroll
      for (int mi = 0; mi < 4; ++mi) {
        fah[mi] = *(const bf16x8*)(bufc + aOff[mi]);
        fal[mi] = *(const bf16x8*)(bufc + 8192 + aOff[mi]);
      }
      __builtin_amdgcn_s_setprio(1);
#pragma unroll
      for (int mi = 0; mi < 4; ++mi)
#pragma unroll
        for (int ni = 0; ni < 4; ++ni) {
          acc[mi][ni] = __builtin_amdgcn_mfma_f32_16x16x32_bf16(fah[mi], fbh[ni], acc[mi][ni], 0, 0, 0);
          acc[mi][ni] = __builtin_amdgcn_mfma_f32_16x16x32_bf16(fah[mi], fbl[ni], acc[mi][ni], 0, 0, 0);
          acc[mi][ni] = __builtin_amdgcn_mfma_f32_16x16x32_bf16(fal[mi], fbh[ni], acc[mi][ni], 0, 0, 0);
        }
      __builtin_amdgcn_s_setprio(0);
      __builtin_amdgcn_sched_barrier(0);
      __builtin_amdgcn_s_barrier();
    }
  } else {
    // fp32 A tile in buf[0,16K): 128B rows, 8-slot XOR swizzle, split in-kernel
    size_t aS[4]; int aL[4];
#pragma unroll
    for (int is = 0; is < 4; ++is) {
      int off = is * 4096 + tid * 16;
      int r = off >> 7;
      int sl = (off >> 4) & 7;
      int col = ((sl ^ (r & 7)) << 2);      // floats
      aS[is] = (arow0 + r) * KDIM + col;
      aL[is] = is * 4096 + w * 1024;
    }
    int a1[4], a2[4];
#pragma unroll
    for (int mi = 0; mi < 4; ++mi) {
      int row = wr * 64 + mi * 16 + fr;
      a1[mi] = row * 128 + (((fq << 1)     ^ (row & 7)) << 4);
      a2[mi] = row * 128 + (((fq << 1) + 1) ^ (row & 7)) * 16;
    }

    auto STAGE = [&](int buf, int k0) {
      char* b = smem + buf * 32768;
#pragma unroll
      for (int is = 0; is < 4; ++is) gld16(Af + aS[is] + k0, b + aL[is]);
#pragma unroll
      for (int is = 0; is < 2; ++is) {
        gld16(Bh + bS[is] + k0, b + 16384 + bL[is]);
        gld16(Bl + bS[is] + k0, b + 24576 + bL[is]);
      }
    };

    STAGE(0, 0);
    for (int t = 0; t < NK; ++t) {
      char* bufc = smem + (t & 1) * 32768;
      if (t + 1 < NK) {
        STAGE((t + 1) & 1, (t + 1) * BK);
        asm volatile("s_waitcnt vmcnt(8)" ::: "memory");
      } else {
        asm volatile("s_waitcnt vmcnt(0)" ::: "memory");
      }
      __builtin_amdgcn_s_barrier();
      __builtin_amdgcn_sched_barrier(0);

      bf16x8 fah[4], fal[4], fbh[4], fbl[4];
#pragma unroll
      for (int ni = 0; ni < 4; ++ni) {
        fbh[ni] = *(const bf16x8*)(bufc + 16384 + bOff[ni]);
        fbl[ni] = *(const bf16x8*)(bufc + 24576 + bOff[ni]);
      }
#pragma unroll
      for (int mi = 0; mi < 4; ++mi) {
        float4 v1 = *(const float4*)(bufc + a1[mi]);
        float4 v2 = *(const float4*)(bufc + a2[mi]);
        float f[8] = {v1.x, v1.y, v1.z, v1.w, v2.x, v2.y, v2.z, v2.w};
        union { bf16x8 v; unsigned short u[8]; } H, L;
#pragma unroll
        for (int q = 0; q < 8; ++q) {
          unsigned short hq = f2bf(f[q]);
          H.u[q] = hq;
          L.u[q] = f2bf(f[q] - bf2f(hq));
        }
        fah[mi] = H.v;
        fal[mi] = L.v;
      }
      __builtin_amdgcn_s_setprio(1);
#pragma unroll
      for (int mi = 0; mi < 4; ++mi)
#pragma unroll
        for (int ni = 0; ni < 4; ++ni) {
          acc[mi][ni] = __builtin_amdgcn_mfma_f32_16x16x32_bf16(fah[mi], fbh[ni], acc[mi][ni], 0, 0, 0);
          acc[mi][ni] = __builtin_amdgcn_mfma_f32_16x16x32_bf16(fah[mi], fbl[ni], acc[mi][ni], 0, 0, 0);
          acc[mi][ni] = __builtin_amdgcn_mfma_f32_16x16x32_bf16(fal[mi], fbh[ni], acc[mi][ni], 0, 0, 0);
        }
      __builtin_amdgcn_s_setprio(0);
      __builtin_amdgcn_sched_barrier(0);
      __builtin_amdgcn_s_barrier();
    }
  }

  // ---- epilogue: acc -> LDS -> linear coalesced P stores
  float* ep = (float*)smem;
  __syncthreads();
#pragma unroll
  for (int half = 0; half < 2; ++half) {
    if (wr == half) {
#pragma unroll
      for (int mi = 0; mi < 4; ++mi)
#pragma unroll
        for (int ni = 0; ni < 4; ++ni)
#pragma unroll
          for (int j = 0; j < 4; ++j) {
            int r = mi * 16 + fq * 4 + j;
            int c = wc * 64 + ni * 16 + fr;
            ep[r * EPS + c] = acc[mi][ni][j];
          }
    }
    __syncthreads();
    for (int i = tid; i < 2048; i += 256) {
      int r = i >> 5;
      int c4 = (i & 31) << 2;
      float4 v = *(const float4*)&ep[r * EPS + c4];
      *(float4*)&P[(arow0 + half * 64 + r) * NDIM + brow0 + c4] = v;
    }
    __syncthreads();
  }
}

// ---------------- pass 2: streaming gather/write (warp-per-row) ----------------
// out[t] = relu(P[word_ids[t]] + Hc[char_ids[t]]), t in order -> sequential writes.
__global__ __launch_bounds__(256) void k_out(const int* __restrict__ wid,
                                             const int* __restrict__ cid,
                                             const float* __restrict__ P,
                                             const float* __restrict__ Hc,
                                             float* __restrict__ out) {
  int w = threadIdx.x >> 6, lane = threadIdx.x & 63;
  int t = blockIdx.x * 4 + w;
  int wd = wid[t], cd = cid[t];
  const f32x4* pr = (const f32x4*)&P[(size_t)wd << 10];
  const f32x4* hr = (const f32x4*)&Hc[(size_t)cd << 10];
  f32x4* orow = (f32x4*)&out[(size_t)t << 10];
#pragma unroll
  for (int ch = 0; ch < 4; ++ch) {
    int c = ch * 64 + lane;
    f32x4 a = pr[c];
    f32x4 h4 = hr[c];
    f32x4 r;
    r[0] = fmaxf(a[0] + h4[0], 0.f);
    r[1] = fmaxf(a[1] + h4[1], 0.f);
    r[2] = fmaxf(a[2] + h4[2], 0.f);
    r[3] = fmaxf(a[3] + h4[3], 0.f);
    __builtin_nontemporal_store(r, &orow[c]);
  }
}

extern "C" void kernel_launch(void* const* d_in, const int* in_sizes, int n_in,
                              void* d_out, int out_size, void* d_ws, size_t ws_size,
                              hipStream_t stream) {
  (void)in_sizes; (void)n_in; (void)out_size;
  const float* word_emb = (const float*)d_in[0];
  const int*   char_ids = (const int*)d_in[1];
  const int*   word_ids = (const int*)d_in[2];
  const float* E        = (const float*)d_in[3];
  const float* W_ih     = (const float*)d_in[4];
  const float* b_ih     = (const float*)d_in[5];
  const float* b_hh     = (const float*)d_in[6];
  const float* W_lin    = (const float*)d_in[7];
  const float* b_lin    = (const float*)d_in[8];
  float* out = (float*)d_out;
  char* ws = (char*)d_ws;

  size_t o = 0;
  auto alloc = [&](size_t b) { size_t r = o; o = (o + b + 255) & ~(size_t)255; return r; };
  size_t oHc = alloc((size_t)NEMB * NDIM * 4);
  size_t oBh = alloc((size_t)NDIM * KDIM * 2);
  size_t oBl = alloc((size_t)NDIM * KDIM * 2);
  size_t oP  = alloc((size_t)NWORDS * NDIM * 4);
  size_t szB = o;
  size_t oAh = alloc((size_t)NWORDS * KDIM * 2);
  size_t oAl = alloc((size_t)NWORDS * KDIM * 2);
  size_t szA = o;

  float* Hc          = (float*)(ws + oHc);
  unsigned short* Bh = (unsigned short*)(ws + oBh);
  unsigned short* Bl = (unsigned short*)(ws + oBl);
  float* P           = (float*)(ws + oP);
  unsigned short* Ah = (unsigned short*)(ws + oAh);
  unsigned short* Al = (unsigned short*)(ws + oAl);

  int grid = (NWORDS / BM) * (NDIM / BN);  // 2048

  if (ws_size >= szA) {
    k_prep<true><<<NEMB + NCONVB_BLKS + NCONVA_BLKS, 256, 0, stream>>>(
        word_emb, E, W_ih, b_ih, b_hh, W_lin, b_lin, Ah, Al, Bh, Bl, Hc);
    k_gemm_p<true><<<grid, 256, 0, stream>>>(word_emb, Ah, Al, Bh, Bl, P);
  } else {
    // Plan B: no pre-split A; stage fp32 A and split in-kernel (ws >= szB).
    k_prep<false><<<NEMB + NCONVB_BLKS, 256, 0, stream>>>(
        word_emb, E, W_ih, b_ih, b_hh, W_lin, b_lin, nullptr, nullptr, Bh, Bl, Hc);
    k_gemm_p<false><<<grid, 256, 0, stream>>>(word_emb, nullptr, nullptr, Bh, Bl, P);
  }
  k_out<<<T_TOTAL / 4, 256, 0, stream>>>(word_ids, char_ids, P, Hc, out);
}

// Round 14
// 413.694 us; speedup vs baseline: 1.9897x; 1.1614x over previous
//
#include <hip/hip_runtime.h>
#include <cstdint>
#include <cstddef>

#define T_TOTAL   131072
#define NWORDS    32768
#define WDIM      1024
#define CDIM      256
#define HID       512
#define NEMB      40
#define KDIM      1024
#define NDIM      1024

#define BM 128
#define BN 128
#define BK 32
#define NK (KDIM / BK)
#define EPS 132   // epilogue LDS row stride (floats): 528B -> bank-even

#define NCONVB_BLKS (NDIM * KDIM / 4 / 256)          // 1024
#define NCONVA_BLKS (NWORDS * KDIM / 4 / 256)        // 32768

typedef __attribute__((ext_vector_type(8))) short bf16x8;
typedef __attribute__((ext_vector_type(4))) float f32x4;
typedef __attribute__((ext_vector_type(4))) unsigned short u16x4;

__device__ __forceinline__ unsigned short f2bf(float x) {
  union { float f; unsigned int u; } v; v.f = x;
  unsigned int r = v.u + 0x7fffu + ((v.u >> 16) & 1u);   // RNE
  return (unsigned short)(r >> 16);
}
__device__ __forceinline__ float bf2f(unsigned short b) {
  union { float f; unsigned int u; } v; v.u = ((unsigned int)b) << 16;
  return v.f;
}

__device__ __forceinline__ void gld16(const void* src, void* lds) {
  __builtin_amdgcn_global_load_lds(
      (const __attribute__((address_space(1))) unsigned int*)src,
      (__attribute__((address_space(3))) unsigned int*)lds, 16, 0, 0);
}

// ---------------- fused prep: LSTM->Hc, W_lin->Bh/Bl, word_emb->Ah ----------------
template <bool DO_A>
__global__ __launch_bounds__(256) void k_prep(
    const float* __restrict__ word_emb, const float* __restrict__ E,
    const float* __restrict__ W_ih, const float* __restrict__ b_ih,
    const float* __restrict__ b_hh, const float* __restrict__ W_lin,
    const float* __restrict__ b_lin,
    unsigned short* __restrict__ Ah,
    unsigned short* __restrict__ Bh, unsigned short* __restrict__ Bl,
    float* __restrict__ Hc) {
  __shared__ float sx[CDIM];
  __shared__ float sh[HID];
  int b = blockIdx.x;
  int tid = threadIdx.x;

  if (b < NEMB) {
    // ---- fused LSTM cell (zero state) + Hc row: Hc[e] = W2 @ h + b_lin
    int e = b;
    sx[tid] = E[e * CDIM + tid];
    __syncthreads();
    const float4* xv = (const float4*)sx;
#pragma unroll
    for (int rep = 0; rep < 2; ++rep) {
      int j = rep * 256 + tid;                       // j in [0,512)
      float si = b_ih[j] + b_hh[j];
      float sg = b_ih[1024 + j] + b_hh[1024 + j];
      float so = b_ih[1536 + j] + b_hh[1536 + j];
      const float4* wi = (const float4*)&W_ih[(size_t)j * CDIM];
      const float4* wg = (const float4*)&W_ih[(size_t)(1024 + j) * CDIM];
      const float4* wo = (const float4*)&W_ih[(size_t)(1536 + j) * CDIM];
      for (int k = 0; k < CDIM / 4; ++k) {
        float4 d = xv[k];
        float4 a = wi[k]; si += a.x*d.x + a.y*d.y + a.z*d.z + a.w*d.w;
        float4 g = wg[k]; sg += g.x*d.x + g.y*d.y + g.z*d.z + g.w*d.w;
        float4 c = wo[k]; so += c.x*d.x + c.y*d.y + c.z*d.z + c.w*d.w;
      }
      float iv = 1.f / (1.f + expf(-si));
      float cv = iv * tanhf(sg);
      float ov = 1.f / (1.f + expf(-so));
      sh[j] = ov * tanhf(cv);
    }
    __syncthreads();
    const float4* hv = (const float4*)sh;
#pragma unroll
    for (int rep = 0; rep < 4; ++rep) {
      int n = rep * 256 + tid;
      float s = b_lin[n];
      const float4* wl = (const float4*)&W_lin[(size_t)n * 1536 + 1024];
      for (int k = 0; k < HID / 4; ++k) {
        float4 a = wl[k], d = hv[k];
        s += a.x*d.x + a.y*d.y + a.z*d.z + a.w*d.w;
      }
      Hc[e * NDIM + n] = s;
    }
    return;
  }
  b -= NEMB;
  if (b < NCONVB_BLKS) {
    // ---- W_lin cols [0,1024) -> Bh/Bl (hi/lo bf16 split; B keeps both terms)
    long idx = ((long)b * 256 + tid) * 4;
    long r = idx >> 10;
    int c = (int)(idx & 1023);
    const float4 v = *(const float4*)&W_lin[r * 1536 + c];
    unsigned short h0 = f2bf(v.x), h1 = f2bf(v.y), h2 = f2bf(v.z), h3 = f2bf(v.w);
    u16x4 H = {h0, h1, h2, h3};
    u16x4 L = {f2bf(v.x - bf2f(h0)), f2bf(v.y - bf2f(h1)),
               f2bf(v.z - bf2f(h2)), f2bf(v.w - bf2f(h3))};
    *(u16x4*)&Bh[idx] = H;
    *(u16x4*)&Bl[idx] = L;
    return;
  }
  if (DO_A) {
    // ---- word_emb (contiguous 32768x1024) -> Ah only (2-term split)
    b -= NCONVB_BLKS;
    long idx = ((long)b * 256 + tid) * 4;
    const float4 v = *(const float4*)&word_emb[idx];
    u16x4 H = {f2bf(v.x), f2bf(v.y), f2bf(v.z), f2bf(v.w)};
    *(u16x4*)&Ah[idx] = H;
  }
}

// ---------------- GEMM (dedup'd words) -> P[32768][1024] ----------------
// P[m][n] ~= sum_k we[m][k]*W[n][k] via 2-term split-bf16: Ah*Bh + Ah*Bl.
// (A's low residual dropped: sigma ~4e-4 per output, << pass margin.)
// 256 thr / 4 waves (2x2, wave tile 64x64), 2 x 24KB dbuf -> 3 blocks/CU,
// counted vmcnt(6). XOR slot-swizzle on the GLOBAL source (LDS dest linear,
// required by global_load_lds) and on the fragment reads -> 0 bank conflicts.
template <bool PRECONV>
__global__ __launch_bounds__(256, 3) void k_gemm_p(
    const float* __restrict__ Af,
    const unsigned short* __restrict__ Ah,
    const unsigned short* __restrict__ Bh, const unsigned short* __restrict__ Bl,
    float* __restrict__ P) {
  __shared__ __align__(16) char smem[PRECONV ? 49152 : 65536];

  int nwg = gridDim.x;
  int bid = blockIdx.x;
  int cpx = nwg >> 3;
  int swz = (bid & 7) * cpx + (bid >> 3);
  int bn = swz & 7;
  int bm = swz >> 3;

  int tid = threadIdx.x;
  int lane = tid & 63;
  int w = tid >> 6;
  int wr = w >> 1, wc = w & 1;
  int fr = lane & 15, fq = lane >> 4;

  size_t arow0 = (size_t)bm * BM;
  size_t brow0 = (size_t)bn * BN;

  f32x4 acc[4][4];
#pragma unroll
  for (int i = 0; i < 4; ++i)
#pragma unroll
    for (int j = 0; j < 4; ++j) acc[i][j] = (f32x4)0.0f;

  int bOff[4];
#pragma unroll
  for (int ni = 0; ni < 4; ++ni) {
    int row = wc * 64 + ni * 16 + fr;
    bOff[ni] = row * 64 + ((fq ^ ((row >> 1) & 3)) << 4);
  }
  size_t bS[2]; int bL[2];
#pragma unroll
  for (int is = 0; is < 2; ++is) {
    int off = is * 4096 + tid * 16;
    int r = off >> 6;
    int sp = (off >> 4) & 3;
    int colE = ((sp ^ ((r >> 1) & 3)) << 3);
    bS[is] = (brow0 + r) * KDIM + colE;
    bL[is] = is * 4096 + w * 1024;
  }
  int aOff[4];
#pragma unroll
  for (int mi = 0; mi < 4; ++mi) {
    int row = wr * 64 + mi * 16 + fr;
    aOff[mi] = row * 64 + ((fq ^ ((row >> 1) & 3)) << 4);
  }

  if (PRECONV) {
    // buffer = [A 8K][Bh 8K][Bl 8K] = 24 KB; dbuf 48 KB -> 3 blocks/CU
    size_t aS[2];
#pragma unroll
    for (int is = 0; is < 2; ++is) {
      int off = is * 4096 + tid * 16;
      int r = off >> 6;
      int sp = (off >> 4) & 3;
      int colE = ((sp ^ ((r >> 1) & 3)) << 3);
      aS[is] = (arow0 + r) * KDIM + colE;
    }

    auto STAGE = [&](int buf, int k0) {     // 6 gld16 / thread
      char* b = smem + buf * 24576;
#pragma unroll
      for (int is = 0; is < 2; ++is) {
        gld16(Ah + aS[is] + k0, b + bL[is]);
        gld16(Bh + bS[is] + k0, b + 8192 + bL[is]);
        gld16(Bl + bS[is] + k0, b + 16384 + bL[is]);
      }
    };

    STAGE(0, 0);
    for (int t = 0; t < NK; ++t) {
      char* bufc = smem + (t & 1) * 24576;
      if (t + 1 < NK) {
        STAGE((t + 1) & 1, (t + 1) * BK);
        asm volatile("s_waitcnt vmcnt(6)" ::: "memory");  // tile t landed, t+1 flying
      } else {
        asm volatile("s_waitcnt vmcnt(0)" ::: "memory");
      }
      __builtin_amdgcn_s_barrier();
      __builtin_amdgcn_sched_barrier(0);

      bf16x8 fah[4], fbh[4], fbl[4];
#pragma unroll
      for (int ni = 0; ni < 4; ++ni) {
        fbh[ni] = *(const bf16x8*)(bufc + 8192 + bOff[ni]);
        fbl[ni] = *(const bf16x8*)(bufc + 16384 + bOff[ni]);
      }
#pragma unroll
      for (int mi = 0; mi < 4; ++mi)
        fah[mi] = *(const bf16x8*)(bufc + aOff[mi]);
      __builtin_amdgcn_s_setprio(1);
#pragma unroll
      for (int mi = 0; mi < 4; ++mi)
#pragma unroll
        for (int ni = 0; ni < 4; ++ni) {
          acc[mi][ni] = __builtin_amdgcn_mfma_f32_16x16x32_bf16(fah[mi], fbh[ni], acc[mi][ni], 0, 0, 0);
          acc[mi][ni] = __builtin_amdgcn_mfma_f32_16x16x32_bf16(fah[mi], fbl[ni], acc[mi][ni], 0, 0, 0);
        }
      __builtin_amdgcn_s_setprio(0);
      __builtin_amdgcn_sched_barrier(0);
      __builtin_amdgcn_s_barrier();
    }
  } else {
    // fp32 A tile in buf[0,16K): 128B rows, 8-slot XOR swizzle, cvt in-kernel
    size_t aS[4]; int aL[4];
#pragma unroll
    for (int is = 0; is < 4; ++is) {
      int off = is * 4096 + tid * 16;
      int r = off >> 7;
      int sl = (off >> 4) & 7;
      int col = ((sl ^ (r & 7)) << 2);      // floats
      aS[is] = (arow0 + r) * KDIM + col;
      aL[is] = is * 4096 + w * 1024;
    }
    int a1[4], a2[4];
#pragma unroll
    for (int mi = 0; mi < 4; ++mi) {
      int row = wr * 64 + mi * 16 + fr;
      a1[mi] = row * 128 + (((fq << 1)     ^ (row & 7)) << 4);
      a2[mi] = row * 128 + (((fq << 1) + 1) ^ (row & 7)) * 16;
    }

    auto STAGE = [&](int buf, int k0) {     // 8 gld16 / thread
      char* b = smem + buf * 32768;
#pragma unroll
      for (int is = 0; is < 4; ++is) gld16(Af + aS[is] + k0, b + aL[is]);
#pragma unroll
      for (int is = 0; is < 2; ++is) {
        gld16(Bh + bS[is] + k0, b + 16384 + bL[is]);
        gld16(Bl + bS[is] + k0, b + 24576 + bL[is]);
      }
    };

    STAGE(0, 0);
    for (int t = 0; t < NK; ++t) {
      char* bufc = smem + (t & 1) * 32768;
      if (t + 1 < NK) {
        STAGE((t + 1) & 1, (t + 1) * BK);
        asm volatile("s_waitcnt vmcnt(8)" ::: "memory");
      } else {
        asm volatile("s_waitcnt vmcnt(0)" ::: "memory");
      }
      __builtin_amdgcn_s_barrier();
      __builtin_amdgcn_sched_barrier(0);

      bf16x8 fah[4], fbh[4], fbl[4];
#pragma unroll
      for (int ni = 0; ni < 4; ++ni) {
        fbh[ni] = *(const bf16x8*)(bufc + 16384 + bOff[ni]);
        fbl[ni] = *(const bf16x8*)(bufc + 24576 + bOff[ni]);
      }
#pragma unroll
      for (int mi = 0; mi < 4; ++mi) {
        float4 v1 = *(const float4*)(bufc + a1[mi]);
        float4 v2 = *(const float4*)(bufc + a2[mi]);
        union { bf16x8 v; unsigned short u[8]; } H;
        H.u[0] = f2bf(v1.x); H.u[1] = f2bf(v1.y); H.u[2] = f2bf(v1.z); H.u[3] = f2bf(v1.w);
        H.u[4] = f2bf(v2.x); H.u[5] = f2bf(v2.y); H.u[6] = f2bf(v2.z); H.u[7] = f2bf(v2.w);
        fah[mi] = H.v;
      }
      __builtin_amdgcn_s_setprio(1);
#pragma unroll
      for (int mi = 0; mi < 4; ++mi)
#pragma unroll
        for (int ni = 0; ni < 4; ++ni) {
          acc[mi][ni] = __builtin_amdgcn_mfma_f32_16x16x32_bf16(fah[mi], fbh[ni], acc[mi][ni], 0, 0, 0);
          acc[mi][ni] = __builtin_amdgcn_mfma_f32_16x16x32_bf16(fah[mi], fbl[ni], acc[mi][ni], 0, 0, 0);
        }
      __builtin_amdgcn_s_setprio(0);
      __builtin_amdgcn_sched_barrier(0);
      __builtin_amdgcn_s_barrier();
    }
  }

  // ---- epilogue: acc -> LDS -> linear coalesced P stores
  float* ep = (float*)smem;
  __syncthreads();
#pragma unroll
  for (int half = 0; half < 2; ++half) {
    if (wr == half) {
#pragma unroll
      for (int mi = 0; mi < 4; ++mi)
#pragma unroll
        for (int ni = 0; ni < 4; ++ni)
#pragma unroll
          for (int j = 0; j < 4; ++j) {
            int r = mi * 16 + fq * 4 + j;
            int c = wc * 64 + ni * 16 + fr;
            ep[r * EPS + c] = acc[mi][ni][j];
          }
    }
    __syncthreads();
    for (int i = tid; i < 2048; i += 256) {
      int r = i >> 5;
      int c4 = (i & 31) << 2;
      float4 v = *(const float4*)&ep[r * EPS + c4];
      *(float4*)&P[(arow0 + half * 64 + r) * NDIM + brow0 + c4] = v;
    }
    __syncthreads();
  }
}

// ---------------- pass 2: streaming gather/write (warp-per-row) ----------------
// out[t] = relu(P[word_ids[t]] + Hc[char_ids[t]]), t in order -> sequential writes.
__global__ __launch_bounds__(256) void k_out(const int* __restrict__ wid,
                                             const int* __restrict__ cid,
                                             const float* __restrict__ P,
                                             const float* __restrict__ Hc,
                                             float* __restrict__ out) {
  int w = threadIdx.x >> 6, lane = threadIdx.x & 63;
  int t = blockIdx.x * 4 + w;
  int wd = wid[t], cd = cid[t];
  const f32x4* pr = (const f32x4*)&P[(size_t)wd << 10];
  const f32x4* hr = (const f32x4*)&Hc[(size_t)cd << 10];
  f32x4* orow = (f32x4*)&out[(size_t)t << 10];
#pragma unroll
  for (int ch = 0; ch < 4; ++ch) {
    int c = ch * 64 + lane;
    f32x4 a = pr[c];
    f32x4 h4 = hr[c];
    f32x4 r;
    r[0] = fmaxf(a[0] + h4[0], 0.f);
    r[1] = fmaxf(a[1] + h4[1], 0.f);
    r[2] = fmaxf(a[2] + h4[2], 0.f);
    r[3] = fmaxf(a[3] + h4[3], 0.f);
    __builtin_nontemporal_store(r, &orow[c]);
  }
}

extern "C" void kernel_launch(void* const* d_in, const int* in_sizes, int n_in,
                              void* d_out, int out_size, void* d_ws, size_t ws_size,
                              hipStream_t stream) {
  (void)in_sizes; (void)n_in; (void)out_size;
  const float* word_emb = (const float*)d_in[0];
  const int*   char_ids = (const int*)d_in[1];
  const int*   word_ids = (const int*)d_in[2];
  const float* E        = (const float*)d_in[3];
  const float* W_ih     = (const float*)d_in[4];
  const float* b_ih     = (const float*)d_in[5];
  const float* b_hh     = (const float*)d_in[6];
  const float* W_lin    = (const float*)d_in[7];
  const float* b_lin    = (const float*)d_in[8];
  float* out = (float*)d_out;
  char* ws = (char*)d_ws;

  size_t o = 0;
  auto alloc = [&](size_t b) { size_t r = o; o = (o + b + 255) & ~(size_t)255; return r; };
  size_t oHc = alloc((size_t)NEMB * NDIM * 4);
  size_t oBh = alloc((size_t)NDIM * KDIM * 2);
  size_t oBl = alloc((size_t)NDIM * KDIM * 2);
  size_t oP  = alloc((size_t)NWORDS * NDIM * 4);
  size_t szB = o;
  size_t oAh = alloc((size_t)NWORDS * KDIM * 2);
  size_t szA = o;

  float* Hc          = (float*)(ws + oHc);
  unsigned short* Bh = (unsigned short*)(ws + oBh);
  unsigned short* Bl = (unsigned short*)(ws + oBl);
  float* P           = (float*)(ws + oP);
  unsigned short* Ah = (unsigned short*)(ws + oAh);

  int grid = (NWORDS / BM) * (NDIM / BN);  // 2048

  if (ws_size >= szA) {
    k_prep<true><<<NEMB + NCONVB_BLKS + NCONVA_BLKS, 256, 0, stream>>>(
        word_emb, E, W_ih, b_ih, b_hh, W_lin, b_lin, Ah, Bh, Bl, Hc);
    k_gemm_p<true><<<grid, 256, 0, stream>>>(word_emb, Ah, Bh, Bl, P);
  } else {
    // Plan B: no pre-split A; stage fp32 A and convert in-kernel (ws >= szB).
    k_prep<false><<<NEMB + NCONVB_BLKS, 256, 0, stream>>>(
        word_emb, E, W_ih, b_ih, b_hh, W_lin, b_lin, nullptr, Bh, Bl, Hc);
    k_gemm_p<false><<<grid, 256, 0, stream>>>(word_emb, nullptr, Bh, Bl, P);
  }
  k_out<<<T_TOTAL / 4, 256, 0, stream>>>(word_ids, char_ids, P, Hc, out);
}